// Round 14
// baseline (296.513 us; speedup 1.0000x reference)
//
#include <hip/hip_runtime.h>
#include <hip/hip_bf16.h>
#include <math.h>

#define BATCH 16
#define CDIM 384
#define HH 32
#define WW 32
#define NPIX 1024
#define MTOK (BATCH * NPIX)  // 16384
#define NHEADS 8
#define DH 48
#define QKVN (3 * CDIM)      // 1152
#define FFN (4 * CDIM)       // 1536

typedef unsigned short u16;
typedef unsigned int u32;
typedef __attribute__((ext_vector_type(8))) short short8;
typedef __attribute__((ext_vector_type(4))) float floatx4;
typedef __attribute__((ext_vector_type(2))) unsigned int uintx2;
typedef __attribute__((ext_vector_type(4))) unsigned int uintx4;

#define MFMA16(a, b, c) __builtin_amdgcn_mfma_f32_16x16x32_bf16(a, b, c, 0, 0, 0)

// async global->LDS 16B copy; LDS dest must be wave-uniform base + lane*16
__device__ __forceinline__ void gl2lds16(const void* g, void* l) {
    __builtin_amdgcn_global_load_lds(
        (const __attribute__((address_space(1))) void*)g,
        (__attribute__((address_space(3))) void*)l, 16, 0, 0);
}

// pack two floats to two bf16 (RNE) in one u32: low16=a, high16=b. 1 VALU op.
__device__ __forceinline__ u32 cvtpk(float a, float b) {
    u32 r;
    asm("v_cvt_pk_bf16_f32 %0, %1, %2" : "=v"(r) : "v"(a), "v"(b));
    return r;
}
// fallback bit-math pack (used by gemm epilogue where compiler schedules fine)
__device__ __forceinline__ u32 pkbf(float a, float b) {
    u32 ua = __float_as_uint(a) + 0x8000u;
    u32 ub = __float_as_uint(b) + 0x8000u;
    return __builtin_amdgcn_perm(ub, ua, 0x07060302u);
}
__device__ __forceinline__ float bf2f(u16 h) { return __uint_as_float(((u32)h) << 16); }

// fast GELU: x*sigmoid(2*0.79788456*(x+0.044715x^3)), sigmoid via exp2+rcp.
// max abs error vs exact-erf GELU ~2e-4 (below bf16 output quantization).
__device__ __forceinline__ float gelu_f(float x) {
    float x2 = x * x;
    float z = x * fmaf(0.10294319f, x2, 2.30220843f);  // 2g*log2(e)
    z = fminf(z, 88.f);                                 // overflow guard
    float e = __builtin_amdgcn_exp2f(z);
    float r = __builtin_amdgcn_rcpf(e + 1.f);
    return x * e * r;
}

// ---------------------------------------------------------------------------
// MERGED: weight transposes (blocks 0..1727) + depthwise conv+PE (1728..4799).
// The two tasks are data-independent; merging hides the wt pass under conv.
// ---------------------------------------------------------------------------
__global__ __launch_bounds__(256) void wt_conv_kernel(
    const float* __restrict__ wqkv, const float* __restrict__ wproj,
    const float* __restrict__ w1, const float* __restrict__ w2,
    __hip_bfloat16* __restrict__ wqkvT, __hip_bfloat16* __restrict__ wprojT,
    __hip_bfloat16* __restrict__ w1T, __hip_bfloat16* __restrict__ w2T,
    const float* __restrict__ x, const float* __restrict__ pos_w,
    const float* __restrict__ pos_b, float* __restrict__ t) {
    __shared__ float xs[64][100];
    __shared__ float os[32][68];
    const int bid = blockIdx.x;
    const int tid = threadIdx.x;

    if (bid < 1728) {
        // ------------------- weight transpose: Wt[n][k] = bf16(W[k][n]) ----
        float(*tile)[33] = (float(*)[33]) & xs[0][0];  // 32x33 floats fit in xs
        int id = bid;
        const float* W;
        __hip_bfloat16* Wt;
        int K, N, tidx;
        if (id < 432)       { W = wqkv;  Wt = wqkvT;  K = 384;  N = 1152; tidx = id; }
        else if (id < 576)  { W = wproj; Wt = wprojT; K = 384;  N = 384;  tidx = id - 432; }
        else if (id < 1152) { W = w1;    Wt = w1T;    K = 384;  N = 1536; tidx = id - 576; }
        else                { W = w2;    Wt = w2T;    K = 1536; N = 384;  tidx = id - 1152; }
        int ntx = N / 32;
        int n0 = (tidx % ntx) * 32, k0 = (tidx / ntx) * 32;
        int tx = tid & 31, ty = tid >> 5;
        for (int i = ty; i < 32; i += 8) tile[i][tx] = W[(size_t)(k0 + i) * N + n0 + tx];
        __syncthreads();
        for (int i = ty; i < 32; i += 8)
            Wt[(size_t)(n0 + i) * K + k0 + tx] = __float2bfloat16(tile[tx][i]);
        return;
    }

    // ---------------------- conv + identity + pos bias ---------------------
    const int id2 = bid - 1728;
    const int cg = id2 % (CDIM / 64);
    const int h = (id2 / (CDIM / 64)) % HH;
    const int b = id2 / ((CDIM / 64) * HH);
    const int c0 = cg * 64;

#pragma unroll
    for (int it = 0; it < 6; ++it) {
        int task = tid + it * 256;
        int c = task / 24, rem = task % 24;
        int row = rem >> 3, f4 = rem & 7;
        int hh = h + row - 1;
        float4 v = {0.f, 0.f, 0.f, 0.f};
        if (hh >= 0 && hh < HH)
            v = *(const float4*)(x + (((size_t)(b * CDIM + c0 + c) * HH + hh) * WW + f4 * 4));
        *(float4*)&xs[c][row * 32 + f4 * 4] = v;
    }
    __syncthreads();

    const int c = tid >> 2, w0 = (tid & 3) * 8;
    float wgt[9];
#pragma unroll
    for (int i = 0; i < 9; ++i) wgt[i] = pos_w[(c0 + c) * 9 + i];
    const float pb = pos_b[c0 + c];
#pragma unroll
    for (int wi = 0; wi < 8; ++wi) {
        int w = w0 + wi;
        float acc = 0.f;
#pragma unroll
        for (int r = 0; r < 3; ++r)
#pragma unroll
            for (int kw = 0; kw < 3; ++kw) {
                int w2 = w + kw - 1;
                if (w2 >= 0 && w2 < WW) acc += xs[c][r * 32 + w2] * wgt[r * 3 + kw];
            }
        os[w][c] = xs[c][32 + w] + acc + pb;
    }
    __syncthreads();

    float* dstb = t + (size_t)(b * NPIX + h * 32) * CDIM + c0;
#pragma unroll
    for (int it = 0; it < 2; ++it) {
        int task = tid + it * 256;
        int px = task >> 4, f4 = task & 15;
        *(float4*)(dstb + (size_t)px * CDIM + f4 * 4) = *(const float4*)&os[px][f4 * 4];
    }
}

// ---------------------------------------------------------------------------
// row LayerNorm over C=384, bf16 output. 128 threads/row.
// ---------------------------------------------------------------------------
__global__ void ln_kernel(const float* __restrict__ in,
                          const float* __restrict__ g,
                          const float* __restrict__ bta,
                          __hip_bfloat16* __restrict__ out) {
    int m = blockIdx.x;
    const float* row = in + (size_t)m * CDIM;
    int tid = threadIdx.x;
    float v0 = row[tid], v1 = row[tid + 128], v2 = row[tid + 256];
    float s = v0 + v1 + v2;
    float ss = v0 * v0 + v1 * v1 + v2 * v2;
#pragma unroll
    for (int off = 32; off > 0; off >>= 1) {
        s += __shfl_down(s, off, 64);
        ss += __shfl_down(ss, off, 64);
    }
    __shared__ float red[4];
    if ((tid & 63) == 0) { red[tid >> 6] = s; red[2 + (tid >> 6)] = ss; }
    __syncthreads();
    float sum = red[0] + red[1], sumsq = red[2] + red[3];
    float mu = sum * (1.f / CDIM);
    float var = sumsq * (1.f / CDIM) - mu * mu;
    float rstd = rsqrtf(var + 1e-5f);
    __hip_bfloat16* orow = out + (size_t)m * CDIM;
    orow[tid]       = __float2bfloat16((v0 - mu) * rstd * g[tid] + bta[tid]);
    orow[tid + 128] = __float2bfloat16((v1 - mu) * rstd * g[tid + 128] + bta[tid + 128]);
    orow[tid + 256] = __float2bfloat16((v2 - mu) * rstd * g[tid + 256] + bta[tid + 256]);
}

// ---------------------------------------------------------------------------
// bf16 MFMA GEMM (proven config): BM=128, XOR pair-line swizzled LDS image
// (conflict-free ds_read_b128, coalescing preserved), DOUBLE-buffered, one
// __syncthreads per K-step. GELU via fast exp2-based tanh-form.
// OUTMODE: 0 = f32 row-major, 1 = bf16 row-major (LDS-staged coalesced
// stores), 2 = f32 NCHW-transposed out, 3 = qkv: Q/K tiles (n0<768) as
// OUTMODE 1 to Cout; V tiles (n0>=768) written TRANSPOSED+SWIZZLED directly
// to Vout (the attn vT layout). ALL instantiations now BN=128 (NF=4):
// 8 ds_read_b128 vs 16 MFMA per K-step — MFMA-balanced (BN=64 was 6:8,
// LDS-read-bound).
// ---------------------------------------------------------------------------
template <int BN, int BK, int RES, int ACT, int OUTMODE>
__global__ __launch_bounds__(256) void gemm_bf16(
    const u16* __restrict__ A, const u16* __restrict__ Bt,
    const float* __restrict__ bias, const float* __restrict__ Res,
    void* __restrict__ Cout, u16* __restrict__ Vout, int N, int K) {
    constexpr int KC = BK / 32;
    constexpr int NF = BN / 32;
    __shared__ __align__(16) u16 As[2][KC][128 * 32];
    __shared__ __align__(16) u16 Bs[2][KC][BN * 32];
    const int tid = threadIdx.x;
    const int lane = tid & 63;
    const int wv = tid >> 6;
    const int qd = lane >> 4;
    const int l16 = lane & 15;
    const int wy = wv >> 1, wx = wv & 1;

    const int id = blockIdx.x;
    const int xcd = id & 7, j = id >> 3;
    const int m0 = (xcd * 16 + (j & 15)) * 128;
    const int n0 = (j >> 4) * BN;

    // Swizzled staging source: slot q holds row 2*(q>>3)+(s>>2), elems
    // (s&3)*8.. where s = (q&7) ^ ((q>>3)&7). Slot q+256 -> same s, row+64.
    const int s0 = (tid & 7) ^ ((tid >> 3) & 7);
    const int srow = 2 * (tid >> 3) + (s0 >> 2);
    const int scol = (s0 & 3) * 8;
    const u16* AgS = A + (size_t)(m0 + srow) * K + scol;
    const u16* BgS = Bt + (size_t)(n0 + srow) * K + scol;

    // Swizzled read offsets: logical (row R, chunk qd) at byte
    // (R>>1)*128 + ((((R&1)<<2)|qd) ^ ((R>>1)&7))*16
    int offA[4], offB[NF];
#pragma unroll
    for (int i = 0; i < 4; ++i) {
        int R = wy * 64 + i * 16 + l16;
        offA[i] = (R >> 1) * 128 + (((((R & 1) << 2) | qd) ^ ((R >> 1) & 7)) << 4);
    }
#pragma unroll
    for (int jj = 0; jj < NF; ++jj) {
        int R = wx * (BN / 2) + jj * 16 + l16;
        offB[jj] = (R >> 1) * 128 + (((((R & 1) << 2) | qd) ^ ((R >> 1) & 7)) << 4);
    }

    const floatx4 fz = {0.f, 0.f, 0.f, 0.f};
    floatx4 acc[4][NF];
#pragma unroll
    for (int i = 0; i < 4; ++i)
#pragma unroll
        for (int jj = 0; jj < NF; ++jj) acc[i][jj] = fz;

    auto stage = [&](int slot, int k0) {
#pragma unroll
        for (int kc = 0; kc < KC; ++kc) {
            char* Ad = (char*)&As[slot][kc][0];
            gl2lds16(AgS + k0 + kc * 32, Ad + tid * 16);
            gl2lds16(AgS + (size_t)64 * K + k0 + kc * 32, Ad + (tid + 256) * 16);
            char* Bd = (char*)&Bs[slot][kc][0];
            gl2lds16(BgS + k0 + kc * 32, Bd + tid * 16);
            if (NF == 4) gl2lds16(BgS + (size_t)64 * K + k0 + kc * 32, Bd + (tid + 256) * 16);
        }
    };

    stage(0, 0);
    const int iters = K / BK;
    for (int it = 0; it < iters; ++it) {
        const int slot = it & 1;
        __syncthreads();
        if (it + 1 < iters) stage(slot ^ 1, (it + 1) * BK);
#pragma unroll
        for (int kc = 0; kc < KC; ++kc) {
            const char* Ab = (const char*)&As[slot][kc][0];
            const char* Bb = (const char*)&Bs[slot][kc][0];
            short8 af[4], bfr[NF];
#pragma unroll
            for (int i = 0; i < 4; ++i) af[i] = *(const short8*)(Ab + offA[i]);
#pragma unroll
            for (int jj = 0; jj < NF; ++jj) bfr[jj] = *(const short8*)(Bb + offB[jj]);
            // swapped operands: D = C^T tile; lane -> (col=qd*4+r, row=l16)
#pragma unroll
            for (int i = 0; i < 4; ++i)
#pragma unroll
                for (int jj = 0; jj < NF; ++jj) acc[i][jj] = MFMA16(bfr[jj], af[i], acc[i][jj]);
        }
    }

    const int rowb = m0 + wy * 64 + l16;
    const int colb = n0 + wx * (BN / 2) + qd * 4;

    if constexpr (OUTMODE == 1 || OUTMODE == 3) {
        if (OUTMODE == 3 && n0 >= 2 * CDIM) {
            // V tile: direct transposed+swizzled stores into Vout (attn vT
            // layout): pos = d*1024 + (key&~63)|(key&7) + ((((key>>3)&7)^(d&7))<<3)
#pragma unroll
            for (int jj = 0; jj < NF; ++jj) {
                float4 bb = *(const float4*)(bias + colb + jj * 16);
#pragma unroll
                for (int i = 0; i < 4; ++i) {
                    floatx4 a = acc[i][jj];
                    int row = rowb + i * 16;
                    int b_ = row >> 10, key = row & 1023;
                    int kb = (key & ~63) | (key & 7);
                    int k3 = (key >> 3) & 7;
                    float vv[4] = {a[0] + bb.x, a[1] + bb.y, a[2] + bb.z, a[3] + bb.w};
#pragma unroll
                    for (int r = 0; r < 4; ++r) {
                        int cv = colb + jj * 16 + r - 2 * CDIM;  // V channel 0..383
                        int h = cv / DH, d = cv - h * DH;
                        Vout[((size_t)(b_ * NHEADS + h) * DH + d) * NPIX + kb +
                             ((k3 ^ (d & 7)) << 3)] = (u16)cvtpk(vv[r], vv[r]);
                    }
                }
            }
        } else {
            // LDS-staged coalesced bf16 epilogue (BN=128 instantiations).
            __syncthreads();  // all waves done reading As/Bs
            char* myl = (wv < 2) ? (char*)(&As[0][0][0]) + wv * 8192
                                 : (char*)(&Bs[0][0][0]) + (wv - 2) * 8192;
#pragma unroll
            for (int jj = 0; jj < NF; ++jj) {
                float4 bb = *(const float4*)(bias + colb + jj * 16);
#pragma unroll
                for (int i = 0; i < 4; ++i) {
                    floatx4 a = acc[i][jj];
                    float v0 = a[0] + bb.x, v1 = a[1] + bb.y, v2 = a[2] + bb.z, v3 = a[3] + bb.w;
                    if (ACT) {
                        v0 = gelu_f(v0);
                        v1 = gelu_f(v1);
                        v2 = gelu_f(v2);
                        v3 = gelu_f(v3);
                    }
                    int row_l = i * 16 + l16;
                    int cbyte = (jj * 32 + qd * 8) ^ ((row_l & 7) << 4);
                    uint2 pk;
                    pk.x = pkbf(v0, v1);
                    pk.y = pkbf(v2, v3);
                    *(uint2*)(myl + row_l * 128 + cbyte) = pk;
                }
            }
            __syncthreads();  // order LDS writes before reads
            const int rl0 = lane >> 3;
            const int cb = (lane & 7) * 16;
            __hip_bfloat16* Cb = (__hip_bfloat16*)Cout +
                                 (size_t)(m0 + wy * 64) * N + n0 + wx * 64 + (lane & 7) * 8;
#pragma unroll
            for (int rr8 = 0; rr8 < 8; ++rr8) {
                int row_l = rr8 * 8 + rl0;
                uint4 v = *(const uint4*)(myl + row_l * 128 + (cb ^ ((row_l & 7) << 4)));
                *(uint4*)(Cb + (size_t)row_l * N) = v;
            }
        }
    } else {
#pragma unroll
        for (int jj = 0; jj < NF; ++jj) {
            int col = colb + jj * 16;
            float4 bb = *(const float4*)(bias + col);
#pragma unroll
            for (int i = 0; i < 4; ++i) {
                int row = rowb + i * 16;
                floatx4 a = acc[i][jj];
                float v0 = a[0] + bb.x, v1 = a[1] + bb.y, v2 = a[2] + bb.z, v3 = a[3] + bb.w;
                if (RES) {
                    float4 rv = *(const float4*)(Res + (size_t)row * N + col);
                    v0 += rv.x; v1 += rv.y; v2 += rv.z; v3 += rv.w;
                }
                if (ACT) {
                    v0 = gelu_f(v0);
                    v1 = gelu_f(v1);
                    v2 = gelu_f(v2);
                    v3 = gelu_f(v3);
                }
                if (OUTMODE == 0) {
                    float4 st = {v0, v1, v2, v3};
                    *(float4*)((float*)Cout + (size_t)row * N + col) = st;
                } else {
                    // NCHW: out[b][c][p]; lane holds 4 consecutive channels at pixel row
                    int b_ = row >> 10, p = row & 1023;
                    float* op = (float*)Cout + ((size_t)(b_ * CDIM + col)) * NPIX + p;
                    op[0] = v0;
                    op[NPIX] = v1;
                    op[2 * NPIX] = v2;
                    op[3 * NPIX] = v3;
                }
            }
        }
    }
}

// ---------------------------------------------------------------------------
// MFMA flash attention: triple-buffered K/V, prefetch distance 2, counted
// per-wave vmcnt + 2x q-block coverage (256 q-rows/block, grid 512).
// ---------------------------------------------------------------------------
__global__ __launch_bounds__(256) void attn_kernel(const u16* __restrict__ qkv,
                                                   const u16* __restrict__ vT,
                                                   __hip_bfloat16* __restrict__ ob) {
    const int id = blockIdx.x;
    const int h = id & 7;
    const int b = (id >> 3) & 15;
    const int qb = id >> 7;                      // [0,4): 256-row q-block
    const int tid = threadIdx.x;
    const int lane = tid & 63, wv = tid >> 6;
    const int qd = lane >> 4, l16 = lane & 15;

    __shared__ u16 Kl[3][65 * 48];               // 3-buf [key][d] + safety row
    __shared__ u16 Vt[3][48 * 64];               // 3-buf [d][key], swizzled image

    const size_t bh = (size_t)b * NPIX * QKVN + (size_t)h * DH;
    const u16* vtb = vT + (size_t)(b * NHEADS + h) * DH * NPIX;

    auto stageK = [&](int kt, int slot) {
        const size_t kbase = bh + (size_t)(kt * 64) * QKVN + CDIM;
        int key = tid / 6, ch = tid - key * 6;
        gl2lds16(qkv + kbase + (size_t)key * QKVN + ch * 8, &Kl[slot][0] + tid * 8);
        if (tid < 128) {
            int t2 = tid + 256;
            int k2 = t2 / 6, c2 = t2 - k2 * 6;
            gl2lds16(qkv + kbase + (size_t)k2 * QKVN + c2 * 8, &Kl[slot][0] + t2 * 8);
        }
    };
    auto stageV = [&](int kt, int slot) {
        const u16* vbase = vtb + (size_t)kt * 64 + (tid & 7) * 8;
        gl2lds16(vbase + (size_t)(tid >> 3) * NPIX, &Vt[slot][0] + tid * 8);
        if (tid < 128)
            gl2lds16(vbase + (size_t)((tid + 256) >> 3) * NPIX, &Vt[slot][0] + (tid + 256) * 8);
    };

    // Q fragments (B-operand), 4 16-row groups covering 256 q-rows:
    // row = qb*256 + (g2>>1)*128 + wv*32 + (g2&1)*16 + l16
    const float qsc = 0.14433756729740643f * 1.4426950408889634f;
    short8 qf[4][2];
    const short8 z8 = {0, 0, 0, 0, 0, 0, 0, 0};
#pragma unroll
    for (int g2 = 0; g2 < 4; ++g2) {
        const int qrow = qb * 256 + (g2 >> 1) * 128 + wv * 32 + (g2 & 1) * 16 + l16;
        const u16* gq = qkv + bh + (size_t)qrow * QKVN;
        short8 q0 = *(const short8*)(gq + qd * 8);
        short8 q1 = (qd < 2) ? *(const short8*)(gq + 32 + qd * 8) : z8;
        uintx4 u0 = __builtin_bit_cast(uintx4, q0);
        uintx4 u1 = __builtin_bit_cast(uintx4, q1);
#pragma unroll
        for (int w = 0; w < 4; ++w) {
            u0[w] = cvtpk(bf2f((u16)(u0[w] & 0xFFFF)) * qsc, bf2f((u16)(u0[w] >> 16)) * qsc);
            u1[w] = cvtpk(bf2f((u16)(u1[w] & 0xFFFF)) * qsc, bf2f((u16)(u1[w] >> 16)) * qsc);
        }
        qf[g2][0] = __builtin_bit_cast(short8, u0);
        qf[g2][1] = __builtin_bit_cast(short8, u1);
    }

    const floatx4 fz = {0.f, 0.f, 0.f, 0.f};
    floatx4 o[4][3];
    floatx4 lacc[4];
    const short8 ones8 = {0x3F80, 0x3F80, 0x3F80, 0x3F80, 0x3F80, 0x3F80, 0x3F80, 0x3F80};
#pragma unroll
    for (int g2 = 0; g2 < 4; ++g2) {
        lacc[g2] = fz;
#pragma unroll
        for (int nt = 0; nt < 3; ++nt) o[g2][nt] = fz;
    }

    // prologue: two stages in flight (prefetch distance 2)
    stageK(0, 0); stageV(0, 0);
    stageK(1, 1); stageV(1, 1);
    const int sw = l16 & 7;

    for (int kt = 0; kt < 16; ++kt) {
        const int cur = kt % 3;
        // Wait for stage(kt) only (stage(kt+1) stays in flight), then barrier.
        // Waves 0-1 issue 4 gl2lds per stage, waves 2-3 issue 2.
        if (kt + 1 < 16) {
            if (wv < 2) asm volatile("s_waitcnt vmcnt(4)\ns_barrier" ::: "memory");
            else        asm volatile("s_waitcnt vmcnt(2)\ns_barrier" ::: "memory");
        } else {
            asm volatile("s_waitcnt vmcnt(0)\ns_barrier" ::: "memory");
        }
        // issue stage(kt+2) into the slot last read at kt-1 (safe: all waves
        // passed the barrier, their kt-1 LDS reads are complete)
        if (kt + 2 < 16) {
            int ns = (kt + 2) % 3;
            stageK(kt + 2, ns);
            stageV(kt + 2, ns);
        }

        // K fragments (A-operand: m=key); overread d>=48 multiplied by qf1=0
        short8 kl[4], kh[4];
#pragma unroll
        for (int t = 0; t < 4; ++t) {
            const u16* kr = &Kl[cur][0] + (t * 16 + l16) * 48;
            kl[t] = *(const short8*)(kr + qd * 8);
            kh[t] = *(const short8*)(kr + 32 + qd * 8);
        }
        // V fragments (A-operand for PV: m=d); swizzled chunk position
        short8 vl[3], vh[3];
#pragma unroll
        for (int nt = 0; nt < 3; ++nt) {
            const u16* vr = &Vt[cur][0] + (nt * 16 + l16) * 64;
            vl[nt] = *(const short8*)(vr + (qd ^ sw) * 8);
            vh[nt] = *(const short8*)(vr + ((qd + 4) ^ sw) * 8);
        }

#pragma unroll
        for (int g2 = 0; g2 < 4; ++g2) {
            // S^T tiles: lane -> (key = t*16+qd*4+r, query = l16)
            u32 pw[4][2];
#pragma unroll
            for (int t = 0; t < 4; ++t) {
                floatx4 a = fz;
                a = MFMA16(kl[t], qf[g2][0], a);
                a = MFMA16(kh[t], qf[g2][1], a);
                float p0 = __builtin_amdgcn_exp2f(a[0]);
                float p1 = __builtin_amdgcn_exp2f(a[1]);
                float p2 = __builtin_amdgcn_exp2f(a[2]);
                float p3 = __builtin_amdgcn_exp2f(a[3]);
                pw[t][0] = cvtpk(p0, p1);  // keys t*16+qd*4+{0,1}, query l16
                pw[t][1] = cvtpk(p2, p3);  // keys t*16+qd*4+{2,3}
            }
            // In-register P^T redistribution: perfect shuffle of 16-lane groups.
            u32 apw[8];
#pragma unroll
            for (int hb2 = 0; hb2 < 2; ++hb2) {
#pragma unroll
                for (int w = 0; w < 2; ++w) {
                    uintx2 P = __builtin_amdgcn_permlane32_swap(
                        pw[2 * hb2][w], pw[2 * hb2 + 1][w], false, false);
                    uintx2 R = __builtin_amdgcn_permlane16_swap(P.x, P.y, false, false);
                    apw[hb2 * 4 + w] = R.x;
                    apw[hb2 * 4 + w + 2] = R.y;
                }
            }
            uintx4 a0v = {apw[0], apw[1], apw[2], apw[3]};
            uintx4 a1v = {apw[4], apw[5], apw[6], apw[7]};
            short8 ap0 = __builtin_bit_cast(short8, a0v);
            short8 ap1 = __builtin_bit_cast(short8, a1v);
            // PV: O^T accumulate; denominator on MFMA pipe (ones-row trick)
#pragma unroll
            for (int nt = 0; nt < 3; ++nt) {
                o[g2][nt] = MFMA16(vl[nt], ap0, o[g2][nt]);
                o[g2][nt] = MFMA16(vh[nt], ap1, o[g2][nt]);
            }
            lacc[g2] = MFMA16(ones8, ap0, lacc[g2]);
            lacc[g2] = MFMA16(ones8, ap1, lacc[g2]);
        }
    }

    // epilogue: lane holds O^T[d=nt*16+qd*4+r][query=l16]; lacc rows identical
    // = full denominator for query l16 (no cross-lane reduction needed).
#pragma unroll
    for (int g2 = 0; g2 < 4; ++g2) {
        float inv = 1.f / lacc[g2][0];
        const int qrow = qb * 256 + (g2 >> 1) * 128 + wv * 32 + (g2 & 1) * 16 + l16;
        __hip_bfloat16* orow = ob + (size_t)(b * NPIX + qrow) * CDIM + h * DH;
#pragma unroll
        for (int nt = 0; nt < 3; ++nt) {
            float v0 = o[g2][nt][0] * inv, v1 = o[g2][nt][1] * inv;
            float v2 = o[g2][nt][2] * inv, v3 = o[g2][nt][3] * inv;
            uint2 w;
            w.x = cvtpk(v0, v1);
            w.y = cvtpk(v2, v3);
            *(uint2*)(orow + nt * 16 + qd * 4) = w;
        }
    }
}

// ---------------------------------------------------------------------------
extern "C" void kernel_launch(void* const* d_in, const int* in_sizes, int n_in,
                              void* d_out, int out_size, void* d_ws, size_t ws_size,
                              hipStream_t stream) {
    const float* x = (const float*)d_in[0];
    const float* pos_w = (const float*)d_in[1];
    const float* pos_b = (const float*)d_in[2];
    const float* g1 = (const float*)d_in[3];
    const float* b1 = (const float*)d_in[4];
    const float* wqkv = (const float*)d_in[5];
    const float* bqkv = (const float*)d_in[6];
    const float* wproj = (const float*)d_in[7];
    const float* bproj = (const float*)d_in[8];
    const float* g2 = (const float*)d_in[9];
    const float* b2 = (const float*)d_in[10];
    const float* w1 = (const float*)d_in[11];
    const float* bf1 = (const float*)d_in[12];
    const float* w2 = (const float*)d_in[13];
    const float* bf2 = (const float*)d_in[14];
    float* out = (float*)d_out;

    char* ws = (char*)d_ws;
    float* t = (float*)ws;                                      // [0, 25.2MB) f32, live whole net
    __hip_bfloat16* xn = (__hip_bfloat16*)(ws + 25165824);      // LN out; dead after its GEMM
    __hip_bfloat16* obb = (__hip_bfloat16*)(ws + 25165824);     // attn out REUSES xn slot
    __hip_bfloat16* wqkvT = (__hip_bfloat16*)(ws + 37748736);
    __hip_bfloat16* wprojT = (__hip_bfloat16*)(ws + 38633472);
    __hip_bfloat16* w1T = (__hip_bfloat16*)(ws + 38928384);
    __hip_bfloat16* w2T = (__hip_bfloat16*)(ws + 40108032);
    char* big = ws + 41287680;
    u16* qkvb = (u16*)big;                                      // [41.3, 79.0MB)
    u16* vTb = (u16*)(big + 37748736);                          // [79.0, 91.6MB) fused vtrans out
    u16* hb = (u16*)big;                                        // mlp1 out reuses qkvb (dead)

    // merged weight-transpose (blocks 0..1727) + conv+PE (1728..4799)
    wt_conv_kernel<<<dim3(1728 + (CDIM / 64) * HH * BATCH), 256, 0, stream>>>(
        wqkv, wproj, w1, w2, wqkvT, wprojT, w1T, w2T, x, pos_w, pos_b, t);
    ln_kernel<<<MTOK, 128, 0, stream>>>(t, g1, b1, xn);
    // qkv: Q/K tiles -> qkvb rows; V tiles -> vTb transposed+swizzled (fused)
    gemm_bf16<128, 32, 0, 0, 3><<<dim3(128 * (QKVN / 128)), 256, 0, stream>>>(
        (const u16*)xn, (const u16*)wqkvT, bqkv, nullptr, qkvb, vTb, QKVN, CDIM);
    attn_kernel<<<dim3(512), 256, 0, stream>>>(qkvb, vTb, obb);
    // proj: BN=128 (MFMA-balanced); grid 128 m-tiles x 3 n-tiles
    gemm_bf16<128, 32, 1, 0, 0><<<dim3(128 * (CDIM / 128)), 256, 0, stream>>>(
        (const u16*)obb, (const u16*)wprojT, bproj, t, t, nullptr, CDIM, CDIM);
    ln_kernel<<<MTOK, 128, 0, stream>>>(t, g2, b2, xn);
    gemm_bf16<128, 32, 0, 1, 1><<<dim3(128 * (FFN / 128)), 256, 0, stream>>>(
        (const u16*)xn, (const u16*)w1T, bf1, nullptr, hb, nullptr, FFN, CDIM);
    // mlp2: BN=128, writes the NCHW output directly (residual from t)
    gemm_bf16<128, 32, 1, 0, 2><<<dim3(128 * (CDIM / 128)), 256, 0, stream>>>(
        (const u16*)hb, (const u16*)w2T, bf2, t, out, nullptr, CDIM, FFN);
}

// Round 15
// 296.330 us; speedup vs baseline: 1.0006x; 1.0006x over previous
//
#include <hip/hip_runtime.h>
#include <hip/hip_bf16.h>
#include <math.h>

#define BATCH 16
#define CDIM 384
#define HH 32
#define WW 32
#define NPIX 1024
#define MTOK (BATCH * NPIX)  // 16384
#define NHEADS 8
#define DH 48
#define QKVN (3 * CDIM)      // 1152
#define FFN (4 * CDIM)       // 1536

typedef unsigned short u16;
typedef unsigned int u32;
typedef __attribute__((ext_vector_type(8))) short short8;
typedef __attribute__((ext_vector_type(4))) float floatx4;
typedef __attribute__((ext_vector_type(2))) unsigned int uintx2;
typedef __attribute__((ext_vector_type(4))) unsigned int uintx4;

#define MFMA16(a, b, c) __builtin_amdgcn_mfma_f32_16x16x32_bf16(a, b, c, 0, 0, 0)

// async global->LDS 16B copy; LDS dest must be wave-uniform base + lane*16
__device__ __forceinline__ void gl2lds16(const void* g, void* l) {
    __builtin_amdgcn_global_load_lds(
        (const __attribute__((address_space(1))) void*)g,
        (__attribute__((address_space(3))) void*)l, 16, 0, 0);
}

// pack two floats to two bf16 (RNE) in one u32: low16=a, high16=b. 1 VALU op.
__device__ __forceinline__ u32 cvtpk(float a, float b) {
    u32 r;
    asm("v_cvt_pk_bf16_f32 %0, %1, %2" : "=v"(r) : "v"(a), "v"(b));
    return r;
}
// fallback bit-math pack (used by gemm epilogue where compiler schedules fine)
__device__ __forceinline__ u32 pkbf(float a, float b) {
    u32 ua = __float_as_uint(a) + 0x8000u;
    u32 ub = __float_as_uint(b) + 0x8000u;
    return __builtin_amdgcn_perm(ub, ua, 0x07060302u);
}
__device__ __forceinline__ float bf2f(u16 h) { return __uint_as_float(((u32)h) << 16); }

// fast GELU: x*sigmoid(2*0.79788456*(x+0.044715x^3)), sigmoid via exp2+rcp.
// max abs error vs exact-erf GELU ~2e-4 (below bf16 output quantization).
__device__ __forceinline__ float gelu_f(float x) {
    float x2 = x * x;
    float z = x * fmaf(0.10294319f, x2, 2.30220843f);  // 2g*log2(e)
    z = fminf(z, 88.f);                                 // overflow guard
    float e = __builtin_amdgcn_exp2f(z);
    float r = __builtin_amdgcn_rcpf(e + 1.f);
    return x * e * r;
}

// ---------------------------------------------------------------------------
// depthwise 3x3 conv + identity + pos bias -> t[(b*N+p)*C+c], coalesced writes.
// ---------------------------------------------------------------------------
__global__ __launch_bounds__(256) void conv_pe_kernel(const float* __restrict__ x,
                                                      const float* __restrict__ pos_w,
                                                      const float* __restrict__ pos_b,
                                                      float* __restrict__ t) {
    __shared__ float xs[64][100];
    __shared__ float os[32][68];
    const int cg = blockIdx.x, h = blockIdx.y, b = blockIdx.z;
    const int tid = threadIdx.x;
    const int c0 = cg * 64;

#pragma unroll
    for (int it = 0; it < 6; ++it) {
        int task = tid + it * 256;
        int c = task / 24, rem = task % 24;
        int row = rem >> 3, f4 = rem & 7;
        int hh = h + row - 1;
        float4 v = {0.f, 0.f, 0.f, 0.f};
        if (hh >= 0 && hh < HH)
            v = *(const float4*)(x + (((size_t)(b * CDIM + c0 + c) * HH + hh) * WW + f4 * 4));
        *(float4*)&xs[c][row * 32 + f4 * 4] = v;
    }
    __syncthreads();

    const int c = tid >> 2, w0 = (tid & 3) * 8;
    float wgt[9];
#pragma unroll
    for (int i = 0; i < 9; ++i) wgt[i] = pos_w[(c0 + c) * 9 + i];
    const float pb = pos_b[c0 + c];
#pragma unroll
    for (int wi = 0; wi < 8; ++wi) {
        int w = w0 + wi;
        float acc = 0.f;
#pragma unroll
        for (int r = 0; r < 3; ++r)
#pragma unroll
            for (int kw = 0; kw < 3; ++kw) {
                int w2 = w + kw - 1;
                if (w2 >= 0 && w2 < WW) acc += xs[c][r * 32 + w2] * wgt[r * 3 + kw];
            }
        os[w][c] = xs[c][32 + w] + acc + pb;
    }
    __syncthreads();

    float* dstb = t + (size_t)(b * NPIX + h * 32) * CDIM + c0;
#pragma unroll
    for (int it = 0; it < 2; ++it) {
        int task = tid + it * 256;
        int px = task >> 4, f4 = task & 15;
        *(float4*)(dstb + (size_t)px * CDIM + f4 * 4) = *(const float4*)&os[px][f4 * 4];
    }
}

// ---------------------------------------------------------------------------
// row LayerNorm over C=384, bf16 output. 128 threads/row.
// ---------------------------------------------------------------------------
__global__ void ln_kernel(const float* __restrict__ in,
                          const float* __restrict__ g,
                          const float* __restrict__ bta,
                          __hip_bfloat16* __restrict__ out) {
    int m = blockIdx.x;
    const float* row = in + (size_t)m * CDIM;
    int tid = threadIdx.x;
    float v0 = row[tid], v1 = row[tid + 128], v2 = row[tid + 256];
    float s = v0 + v1 + v2;
    float ss = v0 * v0 + v1 * v1 + v2 * v2;
#pragma unroll
    for (int off = 32; off > 0; off >>= 1) {
        s += __shfl_down(s, off, 64);
        ss += __shfl_down(ss, off, 64);
    }
    __shared__ float red[4];
    if ((tid & 63) == 0) { red[tid >> 6] = s; red[2 + (tid >> 6)] = ss; }
    __syncthreads();
    float sum = red[0] + red[1], sumsq = red[2] + red[3];
    float mu = sum * (1.f / CDIM);
    float var = sumsq * (1.f / CDIM) - mu * mu;
    float rstd = rsqrtf(var + 1e-5f);
    __hip_bfloat16* orow = out + (size_t)m * CDIM;
    orow[tid]       = __float2bfloat16((v0 - mu) * rstd * g[tid] + bta[tid]);
    orow[tid + 128] = __float2bfloat16((v1 - mu) * rstd * g[tid + 128] + bta[tid + 128]);
    orow[tid + 256] = __float2bfloat16((v2 - mu) * rstd * g[tid + 256] + bta[tid + 256]);
}

// ---------------------------------------------------------------------------
// all 4 weight transposes in ONE dispatch: Wt[n][k] = bf16(W[k][n]).
// ---------------------------------------------------------------------------
__global__ void wt_all_kernel(const float* __restrict__ wqkv, const float* __restrict__ wproj,
                              const float* __restrict__ w1, const float* __restrict__ w2,
                              __hip_bfloat16* __restrict__ wqkvT, __hip_bfloat16* __restrict__ wprojT,
                              __hip_bfloat16* __restrict__ w1T, __hip_bfloat16* __restrict__ w2T) {
    __shared__ float tile[32][33];
    int id = blockIdx.x;
    const float* W;
    __hip_bfloat16* Wt;
    int K, N, tidx;
    if (id < 432)       { W = wqkv;  Wt = wqkvT;  K = 384;  N = 1152; tidx = id; }
    else if (id < 576)  { W = wproj; Wt = wprojT; K = 384;  N = 384;  tidx = id - 432; }
    else if (id < 1152) { W = w1;    Wt = w1T;    K = 384;  N = 1536; tidx = id - 576; }
    else                { W = w2;    Wt = w2T;    K = 1536; N = 384;  tidx = id - 1152; }
    int ntx = N / 32;
    int n0 = (tidx % ntx) * 32, k0 = (tidx / ntx) * 32;
    int tx = threadIdx.x & 31, ty = threadIdx.x >> 5;
    for (int i = ty; i < 32; i += 8) tile[i][tx] = W[(size_t)(k0 + i) * N + n0 + tx];
    __syncthreads();
    for (int i = ty; i < 32; i += 8)
        Wt[(size_t)(n0 + i) * K + k0 + tx] = __float2bfloat16(tile[tx][i]);
}

// ---------------------------------------------------------------------------
// bf16 MFMA GEMM (proven config): BM=128, XOR pair-line swizzled LDS image
// (conflict-free ds_read_b128, coalescing preserved), DOUBLE-buffered, one
// __syncthreads per K-step. GELU via fast exp2-based tanh-form.
// OUTMODE: 0 = f32 row-major, 1 = bf16 row-major (LDS-staged coalesced
// stores), 2 = f32 NCHW-transposed out, 3 = qkv: Q/K tiles (n0<768) as
// OUTMODE 1 to Cout; V tiles (n0>=768) written TRANSPOSED+SWIZZLED directly
// to Vout (the attn vT layout) — replaces the standalone vtrans kernel.
// ---------------------------------------------------------------------------
template <int BN, int BK, int RES, int ACT, int OUTMODE>
__global__ __launch_bounds__(256) void gemm_bf16(
    const u16* __restrict__ A, const u16* __restrict__ Bt,
    const float* __restrict__ bias, const float* __restrict__ Res,
    void* __restrict__ Cout, u16* __restrict__ Vout, int N, int K) {
    constexpr int KC = BK / 32;
    constexpr int NF = BN / 32;
    __shared__ __align__(16) u16 As[2][KC][128 * 32];
    __shared__ __align__(16) u16 Bs[2][KC][BN * 32];
    const int tid = threadIdx.x;
    const int lane = tid & 63;
    const int wv = tid >> 6;
    const int qd = lane >> 4;
    const int l16 = lane & 15;
    const int wy = wv >> 1, wx = wv & 1;

    const int id = blockIdx.x;
    const int xcd = id & 7, j = id >> 3;
    const int m0 = (xcd * 16 + (j & 15)) * 128;
    const int n0 = (j >> 4) * BN;

    // Swizzled staging source: slot q holds row 2*(q>>3)+(s>>2), elems
    // (s&3)*8.. where s = (q&7) ^ ((q>>3)&7). Slot q+256 -> same s, row+64.
    const int s0 = (tid & 7) ^ ((tid >> 3) & 7);
    const int srow = 2 * (tid >> 3) + (s0 >> 2);
    const int scol = (s0 & 3) * 8;
    const u16* AgS = A + (size_t)(m0 + srow) * K + scol;
    const u16* BgS = Bt + (size_t)(n0 + srow) * K + scol;  // NF==2: q<256, rows<64

    // Swizzled read offsets: logical (row R, chunk qd) at byte
    // (R>>1)*128 + ((((R&1)<<2)|qd) ^ ((R>>1)&7))*16
    int offA[4], offB[NF];
#pragma unroll
    for (int i = 0; i < 4; ++i) {
        int R = wy * 64 + i * 16 + l16;
        offA[i] = (R >> 1) * 128 + (((((R & 1) << 2) | qd) ^ ((R >> 1) & 7)) << 4);
    }
#pragma unroll
    for (int jj = 0; jj < NF; ++jj) {
        int R = wx * (BN / 2) + jj * 16 + l16;
        offB[jj] = (R >> 1) * 128 + (((((R & 1) << 2) | qd) ^ ((R >> 1) & 7)) << 4);
    }

    const floatx4 fz = {0.f, 0.f, 0.f, 0.f};
    floatx4 acc[4][NF];
#pragma unroll
    for (int i = 0; i < 4; ++i)
#pragma unroll
        for (int jj = 0; jj < NF; ++jj) acc[i][jj] = fz;

    auto stage = [&](int slot, int k0) {
#pragma unroll
        for (int kc = 0; kc < KC; ++kc) {
            char* Ad = (char*)&As[slot][kc][0];
            gl2lds16(AgS + k0 + kc * 32, Ad + tid * 16);
            gl2lds16(AgS + (size_t)64 * K + k0 + kc * 32, Ad + (tid + 256) * 16);
            char* Bd = (char*)&Bs[slot][kc][0];
            gl2lds16(BgS + k0 + kc * 32, Bd + tid * 16);
            if (NF == 4) gl2lds16(BgS + (size_t)64 * K + k0 + kc * 32, Bd + (tid + 256) * 16);
        }
    };

    stage(0, 0);
    const int iters = K / BK;
    for (int it = 0; it < iters; ++it) {
        const int slot = it & 1;
        __syncthreads();
        if (it + 1 < iters) stage(slot ^ 1, (it + 1) * BK);
#pragma unroll
        for (int kc = 0; kc < KC; ++kc) {
            const char* Ab = (const char*)&As[slot][kc][0];
            const char* Bb = (const char*)&Bs[slot][kc][0];
            short8 af[4], bfr[NF];
#pragma unroll
            for (int i = 0; i < 4; ++i) af[i] = *(const short8*)(Ab + offA[i]);
#pragma unroll
            for (int jj = 0; jj < NF; ++jj) bfr[jj] = *(const short8*)(Bb + offB[jj]);
            // swapped operands: D = C^T tile; lane -> (col=qd*4+r, row=l16)
#pragma unroll
            for (int i = 0; i < 4; ++i)
#pragma unroll
                for (int jj = 0; jj < NF; ++jj) acc[i][jj] = MFMA16(bfr[jj], af[i], acc[i][jj]);
        }
    }

    const int rowb = m0 + wy * 64 + l16;
    const int colb = n0 + wx * (BN / 2) + qd * 4;

    if constexpr (OUTMODE == 1 || OUTMODE == 3) {
        if (OUTMODE == 3 && n0 >= 2 * CDIM) {
            // V tile: direct transposed+swizzled stores into Vout (attn vT
            // layout): pos = d*1024 + (key&~63)|(key&7) + ((((key>>3)&7)^(d&7))<<3)
#pragma unroll
            for (int jj = 0; jj < NF; ++jj) {
                float4 bb = *(const float4*)(bias + colb + jj * 16);
#pragma unroll
                for (int i = 0; i < 4; ++i) {
                    floatx4 a = acc[i][jj];
                    int row = rowb + i * 16;
                    int b_ = row >> 10, key = row & 1023;
                    int kb = (key & ~63) | (key & 7);
                    int k3 = (key >> 3) & 7;
                    float vv[4] = {a[0] + bb.x, a[1] + bb.y, a[2] + bb.z, a[3] + bb.w};
#pragma unroll
                    for (int r = 0; r < 4; ++r) {
                        int cv = colb + jj * 16 + r - 2 * CDIM;  // V channel 0..383
                        int h = cv / DH, d = cv - h * DH;
                        Vout[((size_t)(b_ * NHEADS + h) * DH + d) * NPIX + kb +
                             ((k3 ^ (d & 7)) << 3)] = (u16)cvtpk(vv[r], vv[r]);
                    }
                }
            }
        } else {
            // LDS-staged coalesced bf16 epilogue (BN=128 instantiations).
            __syncthreads();  // all waves done reading As/Bs
            char* myl = (wv < 2) ? (char*)(&As[0][0][0]) + wv * 8192
                                 : (char*)(&Bs[0][0][0]) + (wv - 2) * 8192;
#pragma unroll
            for (int jj = 0; jj < NF; ++jj) {
                float4 bb = *(const float4*)(bias + colb + jj * 16);
#pragma unroll
                for (int i = 0; i < 4; ++i) {
                    floatx4 a = acc[i][jj];
                    float v0 = a[0] + bb.x, v1 = a[1] + bb.y, v2 = a[2] + bb.z, v3 = a[3] + bb.w;
                    if (ACT) {
                        v0 = gelu_f(v0);
                        v1 = gelu_f(v1);
                        v2 = gelu_f(v2);
                        v3 = gelu_f(v3);
                    }
                    int row_l = i * 16 + l16;
                    int cbyte = (jj * 32 + qd * 8) ^ ((row_l & 7) << 4);
                    uint2 pk;
                    pk.x = pkbf(v0, v1);
                    pk.y = pkbf(v2, v3);
                    *(uint2*)(myl + row_l * 128 + cbyte) = pk;
                }
            }
            __syncthreads();  // order LDS writes before reads
            const int rl0 = lane >> 3;
            const int cb = (lane & 7) * 16;
            __hip_bfloat16* Cb = (__hip_bfloat16*)Cout +
                                 (size_t)(m0 + wy * 64) * N + n0 + wx * 64 + (lane & 7) * 8;
#pragma unroll
            for (int rr8 = 0; rr8 < 8; ++rr8) {
                int row_l = rr8 * 8 + rl0;
                uint4 v = *(const uint4*)(myl + row_l * 128 + (cb ^ ((row_l & 7) << 4)));
                *(uint4*)(Cb + (size_t)row_l * N) = v;
            }
        }
    } else {
#pragma unroll
        for (int jj = 0; jj < NF; ++jj) {
            int col = colb + jj * 16;
            float4 bb = *(const float4*)(bias + col);
#pragma unroll
            for (int i = 0; i < 4; ++i) {
                int row = rowb + i * 16;
                floatx4 a = acc[i][jj];
                float v0 = a[0] + bb.x, v1 = a[1] + bb.y, v2 = a[2] + bb.z, v3 = a[3] + bb.w;
                if (RES) {
                    float4 rv = *(const float4*)(Res + (size_t)row * N + col);
                    v0 += rv.x; v1 += rv.y; v2 += rv.z; v3 += rv.w;
                }
                if (ACT) {
                    v0 = gelu_f(v0);
                    v1 = gelu_f(v1);
                    v2 = gelu_f(v2);
                    v3 = gelu_f(v3);
                }
                if (OUTMODE == 0) {
                    float4 st = {v0, v1, v2, v3};
                    *(float4*)((float*)Cout + (size_t)row * N + col) = st;
                } else {
                    // NCHW: out[b][c][p]; lane holds 4 consecutive channels at pixel row
                    int b_ = row >> 10, p = row & 1023;
                    float* op = (float*)Cout + ((size_t)(b_ * CDIM + col)) * NPIX + p;
                    op[0] = v0;
                    op[NPIX] = v1;
                    op[2 * NPIX] = v2;
                    op[3 * NPIX] = v3;
                }
            }
        }
    }
}

// ---------------------------------------------------------------------------
// MFMA flash attention: triple-buffered K/V, prefetch distance 2, counted
// per-wave vmcnt + 2x q-block coverage (256 q-rows/block, grid 512).
// ---------------------------------------------------------------------------
__global__ __launch_bounds__(256) void attn_kernel(const u16* __restrict__ qkv,
                                                   const u16* __restrict__ vT,
                                                   __hip_bfloat16* __restrict__ ob) {
    const int id = blockIdx.x;
    const int h = id & 7;
    const int b = (id >> 3) & 15;
    const int qb = id >> 7;                      // [0,4): 256-row q-block
    const int tid = threadIdx.x;
    const int lane = tid & 63, wv = tid >> 6;
    const int qd = lane >> 4, l16 = lane & 15;

    __shared__ u16 Kl[3][65 * 48];               // 3-buf [key][d] + safety row
    __shared__ u16 Vt[3][48 * 64];               // 3-buf [d][key], swizzled image

    const size_t bh = (size_t)b * NPIX * QKVN + (size_t)h * DH;
    const u16* vtb = vT + (size_t)(b * NHEADS + h) * DH * NPIX;

    auto stageK = [&](int kt, int slot) {
        const size_t kbase = bh + (size_t)(kt * 64) * QKVN + CDIM;
        int key = tid / 6, ch = tid - key * 6;
        gl2lds16(qkv + kbase + (size_t)key * QKVN + ch * 8, &Kl[slot][0] + tid * 8);
        if (tid < 128) {
            int t2 = tid + 256;
            int k2 = t2 / 6, c2 = t2 - k2 * 6;
            gl2lds16(qkv + kbase + (size_t)k2 * QKVN + c2 * 8, &Kl[slot][0] + t2 * 8);
        }
    };
    auto stageV = [&](int kt, int slot) {
        const u16* vbase = vtb + (size_t)kt * 64 + (tid & 7) * 8;
        gl2lds16(vbase + (size_t)(tid >> 3) * NPIX, &Vt[slot][0] + tid * 8);
        if (tid < 128)
            gl2lds16(vbase + (size_t)((tid + 256) >> 3) * NPIX, &Vt[slot][0] + (tid + 256) * 8);
    };

    // Q fragments (B-operand), 4 16-row groups covering 256 q-rows:
    // row = qb*256 + (g2>>1)*128 + wv*32 + (g2&1)*16 + l16
    const float qsc = 0.14433756729740643f * 1.4426950408889634f;
    short8 qf[4][2];
    const short8 z8 = {0, 0, 0, 0, 0, 0, 0, 0};
#pragma unroll
    for (int g2 = 0; g2 < 4; ++g2) {
        const int qrow = qb * 256 + (g2 >> 1) * 128 + wv * 32 + (g2 & 1) * 16 + l16;
        const u16* gq = qkv + bh + (size_t)qrow * QKVN;
        short8 q0 = *(const short8*)(gq + qd * 8);
        short8 q1 = (qd < 2) ? *(const short8*)(gq + 32 + qd * 8) : z8;
        uintx4 u0 = __builtin_bit_cast(uintx4, q0);
        uintx4 u1 = __builtin_bit_cast(uintx4, q1);
#pragma unroll
        for (int w = 0; w < 4; ++w) {
            u0[w] = cvtpk(bf2f((u16)(u0[w] & 0xFFFF)) * qsc, bf2f((u16)(u0[w] >> 16)) * qsc);
            u1[w] = cvtpk(bf2f((u16)(u1[w] & 0xFFFF)) * qsc, bf2f((u16)(u1[w] >> 16)) * qsc);
        }
        qf[g2][0] = __builtin_bit_cast(short8, u0);
        qf[g2][1] = __builtin_bit_cast(short8, u1);
    }

    const floatx4 fz = {0.f, 0.f, 0.f, 0.f};
    floatx4 o[4][3];
    floatx4 lacc[4];
    const short8 ones8 = {0x3F80, 0x3F80, 0x3F80, 0x3F80, 0x3F80, 0x3F80, 0x3F80, 0x3F80};
#pragma unroll
    for (int g2 = 0; g2 < 4; ++g2) {
        lacc[g2] = fz;
#pragma unroll
        for (int nt = 0; nt < 3; ++nt) o[g2][nt] = fz;
    }

    // prologue: two stages in flight (prefetch distance 2)
    stageK(0, 0); stageV(0, 0);
    stageK(1, 1); stageV(1, 1);
    const int sw = l16 & 7;

    for (int kt = 0; kt < 16; ++kt) {
        const int cur = kt % 3;
        // Wait for stage(kt) only (stage(kt+1) stays in flight), then barrier.
        // Waves 0-1 issue 4 gl2lds per stage, waves 2-3 issue 2.
        if (kt + 1 < 16) {
            if (wv < 2) asm volatile("s_waitcnt vmcnt(4)\ns_barrier" ::: "memory");
            else        asm volatile("s_waitcnt vmcnt(2)\ns_barrier" ::: "memory");
        } else {
            asm volatile("s_waitcnt vmcnt(0)\ns_barrier" ::: "memory");
        }
        // issue stage(kt+2) into the slot last read at kt-1 (safe: all waves
        // passed the barrier, their kt-1 LDS reads are complete)
        if (kt + 2 < 16) {
            int ns = (kt + 2) % 3;
            stageK(kt + 2, ns);
            stageV(kt + 2, ns);
        }

        // K fragments (A-operand: m=key); overread d>=48 multiplied by qf1=0
        short8 kl[4], kh[4];
#pragma unroll
        for (int t = 0; t < 4; ++t) {
            const u16* kr = &Kl[cur][0] + (t * 16 + l16) * 48;
            kl[t] = *(const short8*)(kr + qd * 8);
            kh[t] = *(const short8*)(kr + 32 + qd * 8);
        }
        // V fragments (A-operand for PV: m=d); swizzled chunk position
        short8 vl[3], vh[3];
#pragma unroll
        for (int nt = 0; nt < 3; ++nt) {
            const u16* vr = &Vt[cur][0] + (nt * 16 + l16) * 64;
            vl[nt] = *(const short8*)(vr + (qd ^ sw) * 8);
            vh[nt] = *(const short8*)(vr + ((qd + 4) ^ sw) * 8);
        }

#pragma unroll
        for (int g2 = 0; g2 < 4; ++g2) {
            // S^T tiles: lane -> (key = t*16+qd*4+r, query = l16)
            u32 pw[4][2];
#pragma unroll
            for (int t = 0; t < 4; ++t) {
                floatx4 a = fz;
                a = MFMA16(kl[t], qf[g2][0], a);
                a = MFMA16(kh[t], qf[g2][1], a);
                float p0 = __builtin_amdgcn_exp2f(a[0]);
                float p1 = __builtin_amdgcn_exp2f(a[1]);
                float p2 = __builtin_amdgcn_exp2f(a[2]);
                float p3 = __builtin_amdgcn_exp2f(a[3]);
                pw[t][0] = cvtpk(p0, p1);  // keys t*16+qd*4+{0,1}, query l16
                pw[t][1] = cvtpk(p2, p3);  // keys t*16+qd*4+{2,3}
            }
            // In-register P^T redistribution: perfect shuffle of 16-lane groups.
            u32 apw[8];
#pragma unroll
            for (int hb2 = 0; hb2 < 2; ++hb2) {
#pragma unroll
                for (int w = 0; w < 2; ++w) {
                    uintx2 P = __builtin_amdgcn_permlane32_swap(
                        pw[2 * hb2][w], pw[2 * hb2 + 1][w], false, false);
                    uintx2 R = __builtin_amdgcn_permlane16_swap(P.x, P.y, false, false);
                    apw[hb2 * 4 + w] = R.x;
                    apw[hb2 * 4 + w + 2] = R.y;
                }
            }
            uintx4 a0v = {apw[0], apw[1], apw[2], apw[3]};
            uintx4 a1v = {apw[4], apw[5], apw[6], apw[7]};
            short8 ap0 = __builtin_bit_cast(short8, a0v);
            short8 ap1 = __builtin_bit_cast(short8, a1v);
            // PV: O^T accumulate; denominator on MFMA pipe (ones-row trick)
#pragma unroll
            for (int nt = 0; nt < 3; ++nt) {
                o[g2][nt] = MFMA16(vl[nt], ap0, o[g2][nt]);
                o[g2][nt] = MFMA16(vh[nt], ap1, o[g2][nt]);
            }
            lacc[g2] = MFMA16(ones8, ap0, lacc[g2]);
            lacc[g2] = MFMA16(ones8, ap1, lacc[g2]);
        }
    }

    // epilogue: lane holds O^T[d=nt*16+qd*4+r][query=l16]; lacc rows identical
    // = full denominator for query l16 (no cross-lane reduction needed).
#pragma unroll
    for (int g2 = 0; g2 < 4; ++g2) {
        float inv = 1.f / lacc[g2][0];
        const int qrow = qb * 256 + (g2 >> 1) * 128 + wv * 32 + (g2 & 1) * 16 + l16;
        __hip_bfloat16* orow = ob + (size_t)(b * NPIX + qrow) * CDIM + h * DH;
#pragma unroll
        for (int nt = 0; nt < 3; ++nt) {
            float v0 = o[g2][nt][0] * inv, v1 = o[g2][nt][1] * inv;
            float v2 = o[g2][nt][2] * inv, v3 = o[g2][nt][3] * inv;
            uint2 w;
            w.x = cvtpk(v0, v1);
            w.y = cvtpk(v2, v3);
            *(uint2*)(orow + nt * 16 + qd * 4) = w;
        }
    }
}

// ---------------------------------------------------------------------------
extern "C" void kernel_launch(void* const* d_in, const int* in_sizes, int n_in,
                              void* d_out, int out_size, void* d_ws, size_t ws_size,
                              hipStream_t stream) {
    const float* x = (const float*)d_in[0];
    const float* pos_w = (const float*)d_in[1];
    const float* pos_b = (const float*)d_in[2];
    const float* g1 = (const float*)d_in[3];
    const float* b1 = (const float*)d_in[4];
    const float* wqkv = (const float*)d_in[5];
    const float* bqkv = (const float*)d_in[6];
    const float* wproj = (const float*)d_in[7];
    const float* bproj = (const float*)d_in[8];
    const float* g2 = (const float*)d_in[9];
    const float* b2 = (const float*)d_in[10];
    const float* w1 = (const float*)d_in[11];
    const float* bf1 = (const float*)d_in[12];
    const float* w2 = (const float*)d_in[13];
    const float* bf2 = (const float*)d_in[14];
    float* out = (float*)d_out;

    char* ws = (char*)d_ws;
    float* t = (float*)ws;                                      // [0, 25.2MB) f32, live whole net
    __hip_bfloat16* xn = (__hip_bfloat16*)(ws + 25165824);      // LN out; dead after its GEMM
    __hip_bfloat16* obb = (__hip_bfloat16*)(ws + 25165824);     // attn out REUSES xn slot
    __hip_bfloat16* wqkvT = (__hip_bfloat16*)(ws + 37748736);
    __hip_bfloat16* wprojT = (__hip_bfloat16*)(ws + 38633472);
    __hip_bfloat16* w1T = (__hip_bfloat16*)(ws + 38928384);
    __hip_bfloat16* w2T = (__hip_bfloat16*)(ws + 40108032);
    char* big = ws + 41287680;
    u16* qkvb = (u16*)big;                                      // [41.3, 79.0MB)
    u16* vTb = (u16*)(big + 37748736);                          // [79.0, 91.6MB) fused vtrans out
    u16* hb = (u16*)big;                                        // mlp1 out reuses qkvb (dead)

    wt_all_kernel<<<dim3(1728), 256, 0, stream>>>(wqkv, wproj, w1, w2,
                                                  wqkvT, wprojT, w1T, w2T);
    conv_pe_kernel<<<dim3(CDIM / 64, HH, BATCH), 256, 0, stream>>>(x, pos_w, pos_b, t);
    ln_kernel<<<MTOK, 128, 0, stream>>>(t, g1, b1, xn);
    // qkv: Q/K tiles -> qkvb rows; V tiles -> vTb transposed+swizzled (fused)
    gemm_bf16<128, 32, 0, 0, 3><<<dim3(128 * (QKVN / 128)), 256, 0, stream>>>(
        (const u16*)xn, (const u16*)wqkvT, bqkv, nullptr, qkvb, vTb, QKVN, CDIM);
    attn_kernel<<<dim3(512), 256, 0, stream>>>(qkvb, vTb, obb);
    gemm_bf16<64, 64, 1, 0, 0><<<dim3(128 * (CDIM / 64)), 256, 0, stream>>>(
        (const u16*)obb, (const u16*)wprojT, bproj, t, t, nullptr, CDIM, CDIM);
    ln_kernel<<<MTOK, 128, 0, stream>>>(t, g2, b2, xn);
    gemm_bf16<128, 32, 0, 1, 1><<<dim3(128 * (FFN / 128)), 256, 0, stream>>>(
        (const u16*)xn, (const u16*)w1T, bf1, nullptr, hb, nullptr, FFN, CDIM);
    // mlp2 writes the NCHW output directly (residual from t, transposed store)
    gemm_bf16<64, 64, 1, 0, 2><<<dim3(128 * (CDIM / 64)), 256, 0, stream>>>(
        (const u16*)hb, (const u16*)w2T, bf2, t, out, nullptr, CDIM, FFN);
}

// Round 16
// 290.992 us; speedup vs baseline: 1.0190x; 1.0183x over previous
//
#include <hip/hip_runtime.h>
#include <hip/hip_bf16.h>
#include <math.h>

#define BATCH 16
#define CDIM 384
#define HH 32
#define WW 32
#define NPIX 1024
#define MTOK (BATCH * NPIX)  // 16384
#define NHEADS 8
#define DH 48
#define QKVN (3 * CDIM)      // 1152
#define FFN (4 * CDIM)       // 1536

typedef unsigned short u16;
typedef unsigned int u32;
typedef __attribute__((ext_vector_type(8))) short short8;
typedef __attribute__((ext_vector_type(4))) float floatx4;
typedef __attribute__((ext_vector_type(2))) unsigned int uintx2;
typedef __attribute__((ext_vector_type(4))) unsigned int uintx4;

#define MFMA16(a, b, c) __builtin_amdgcn_mfma_f32_16x16x32_bf16(a, b, c, 0, 0, 0)

// async global->LDS 16B copy; LDS dest must be wave-uniform base + lane*16
__device__ __forceinline__ void gl2lds16(const void* g, void* l) {
    __builtin_amdgcn_global_load_lds(
        (const __attribute__((address_space(1))) void*)g,
        (__attribute__((address_space(3))) void*)l, 16, 0, 0);
}

// pack two floats to two bf16 (RNE) in one u32: low16=a, high16=b. 1 VALU op.
__device__ __forceinline__ u32 cvtpk(float a, float b) {
    u32 r;
    asm("v_cvt_pk_bf16_f32 %0, %1, %2" : "=v"(r) : "v"(a), "v"(b));
    return r;
}
// fallback bit-math pack (used by gemm epilogue where compiler schedules fine)
__device__ __forceinline__ u32 pkbf(float a, float b) {
    u32 ua = __float_as_uint(a) + 0x8000u;
    u32 ub = __float_as_uint(b) + 0x8000u;
    return __builtin_amdgcn_perm(ub, ua, 0x07060302u);
}
__device__ __forceinline__ float bf2f(u16 h) { return __uint_as_float(((u32)h) << 16); }

// fast GELU: x*sigmoid(2*0.79788456*(x+0.044715x^3)), sigmoid via exp2+rcp.
// max abs error vs exact-erf GELU ~2e-4 (below bf16 output quantization).
__device__ __forceinline__ float gelu_f(float x) {
    float x2 = x * x;
    float z = x * fmaf(0.10294319f, x2, 2.30220843f);  // 2g*log2(e)
    z = fminf(z, 88.f);                                 // overflow guard
    float e = __builtin_amdgcn_exp2f(z);
    float r = __builtin_amdgcn_rcpf(e + 1.f);
    return x * e * r;
}

// ---------------------------------------------------------------------------
// depthwise 3x3 conv + identity + pos bias -> t[(b*N+p)*C+c] in BF16
// (residual stream stored bf16: halves HBM traffic on t).
// ---------------------------------------------------------------------------
__global__ __launch_bounds__(256) void conv_pe_kernel(const float* __restrict__ x,
                                                      const float* __restrict__ pos_w,
                                                      const float* __restrict__ pos_b,
                                                      u16* __restrict__ t) {
    __shared__ float xs[64][100];
    __shared__ float os[32][68];
    const int cg = blockIdx.x, h = blockIdx.y, b = blockIdx.z;
    const int tid = threadIdx.x;
    const int c0 = cg * 64;

#pragma unroll
    for (int it = 0; it < 6; ++it) {
        int task = tid + it * 256;
        int c = task / 24, rem = task % 24;
        int row = rem >> 3, f4 = rem & 7;
        int hh = h + row - 1;
        float4 v = {0.f, 0.f, 0.f, 0.f};
        if (hh >= 0 && hh < HH)
            v = *(const float4*)(x + (((size_t)(b * CDIM + c0 + c) * HH + hh) * WW + f4 * 4));
        *(float4*)&xs[c][row * 32 + f4 * 4] = v;
    }
    __syncthreads();

    const int c = tid >> 2, w0 = (tid & 3) * 8;
    float wgt[9];
#pragma unroll
    for (int i = 0; i < 9; ++i) wgt[i] = pos_w[(c0 + c) * 9 + i];
    const float pb = pos_b[c0 + c];
#pragma unroll
    for (int wi = 0; wi < 8; ++wi) {
        int w = w0 + wi;
        float acc = 0.f;
#pragma unroll
        for (int r = 0; r < 3; ++r)
#pragma unroll
            for (int kw = 0; kw < 3; ++kw) {
                int w2 = w + kw - 1;
                if (w2 >= 0 && w2 < WW) acc += xs[c][r * 32 + w2] * wgt[r * 3 + kw];
            }
        os[w][c] = xs[c][32 + w] + acc + pb;
    }
    __syncthreads();

    u16* dstb = t + (size_t)(b * NPIX + h * 32) * CDIM + c0;
#pragma unroll
    for (int it = 0; it < 2; ++it) {
        int task = tid + it * 256;
        int px = task >> 4, f4 = task & 15;
        float4 v = *(const float4*)&os[px][f4 * 4];
        uint2 pk;
        pk.x = pkbf(v.x, v.y);
        pk.y = pkbf(v.z, v.w);
        *(uint2*)(dstb + (size_t)px * CDIM + f4 * 4) = pk;
    }
}

// ---------------------------------------------------------------------------
// row LayerNorm over C=384 (bf16 input), bf16 output. 128 threads/row.
// ---------------------------------------------------------------------------
__global__ void ln_kernel(const u16* __restrict__ in,
                          const float* __restrict__ g,
                          const float* __restrict__ bta,
                          __hip_bfloat16* __restrict__ out) {
    int m = blockIdx.x;
    const u16* row = in + (size_t)m * CDIM;
    int tid = threadIdx.x;
    float v0 = bf2f(row[tid]), v1 = bf2f(row[tid + 128]), v2 = bf2f(row[tid + 256]);
    float s = v0 + v1 + v2;
    float ss = v0 * v0 + v1 * v1 + v2 * v2;
#pragma unroll
    for (int off = 32; off > 0; off >>= 1) {
        s += __shfl_down(s, off, 64);
        ss += __shfl_down(ss, off, 64);
    }
    __shared__ float red[4];
    if ((tid & 63) == 0) { red[tid >> 6] = s; red[2 + (tid >> 6)] = ss; }
    __syncthreads();
    float sum = red[0] + red[1], sumsq = red[2] + red[3];
    float mu = sum * (1.f / CDIM);
    float var = sumsq * (1.f / CDIM) - mu * mu;
    float rstd = rsqrtf(var + 1e-5f);
    __hip_bfloat16* orow = out + (size_t)m * CDIM;
    orow[tid]       = __float2bfloat16((v0 - mu) * rstd * g[tid] + bta[tid]);
    orow[tid + 128] = __float2bfloat16((v1 - mu) * rstd * g[tid + 128] + bta[tid + 128]);
    orow[tid + 256] = __float2bfloat16((v2 - mu) * rstd * g[tid + 256] + bta[tid + 256]);
}

// ---------------------------------------------------------------------------
// all 4 weight transposes in ONE dispatch: Wt[n][k] = bf16(W[k][n]).
// ---------------------------------------------------------------------------
__global__ void wt_all_kernel(const float* __restrict__ wqkv, const float* __restrict__ wproj,
                              const float* __restrict__ w1, const float* __restrict__ w2,
                              __hip_bfloat16* __restrict__ wqkvT, __hip_bfloat16* __restrict__ wprojT,
                              __hip_bfloat16* __restrict__ w1T, __hip_bfloat16* __restrict__ w2T) {
    __shared__ float tile[32][33];
    int id = blockIdx.x;
    const float* W;
    __hip_bfloat16* Wt;
    int K, N, tidx;
    if (id < 432)       { W = wqkv;  Wt = wqkvT;  K = 384;  N = 1152; tidx = id; }
    else if (id < 576)  { W = wproj; Wt = wprojT; K = 384;  N = 384;  tidx = id - 432; }
    else if (id < 1152) { W = w1;    Wt = w1T;    K = 384;  N = 1536; tidx = id - 576; }
    else                { W = w2;    Wt = w2T;    K = 1536; N = 384;  tidx = id - 1152; }
    int ntx = N / 32;
    int n0 = (tidx % ntx) * 32, k0 = (tidx / ntx) * 32;
    int tx = threadIdx.x & 31, ty = threadIdx.x >> 5;
    for (int i = ty; i < 32; i += 8) tile[i][tx] = W[(size_t)(k0 + i) * N + n0 + tx];
    __syncthreads();
    for (int i = ty; i < 32; i += 8)
        Wt[(size_t)(n0 + i) * K + k0 + tx] = __float2bfloat16(tile[tx][i]);
}

// ---------------------------------------------------------------------------
// bf16 MFMA GEMM (proven config): BM=128, XOR pair-line swizzled LDS image,
// DOUBLE-buffered, one __syncthreads per K-step. Residual (Res) is BF16.
// OUTMODE: 0 = bf16 row-major scattered (+Res), 1 = bf16 row-major
// (LDS-staged coalesced stores), 2 = f32 NCHW-transposed out (+Res),
// 3 = qkv: Q/K tiles as OUTMODE 1; V tiles transposed+swizzled to Vout.
// ---------------------------------------------------------------------------
template <int BN, int BK, int RES, int ACT, int OUTMODE>
__global__ __launch_bounds__(256) void gemm_bf16(
    const u16* __restrict__ A, const u16* __restrict__ Bt,
    const float* __restrict__ bias, const u16* __restrict__ Res,
    void* __restrict__ Cout, u16* __restrict__ Vout, int N, int K) {
    constexpr int KC = BK / 32;
    constexpr int NF = BN / 32;
    __shared__ __align__(16) u16 As[2][KC][128 * 32];
    __shared__ __align__(16) u16 Bs[2][KC][BN * 32];
    const int tid = threadIdx.x;
    const int lane = tid & 63;
    const int wv = tid >> 6;
    const int qd = lane >> 4;
    const int l16 = lane & 15;
    const int wy = wv >> 1, wx = wv & 1;

    const int id = blockIdx.x;
    const int xcd = id & 7, j = id >> 3;
    const int m0 = (xcd * 16 + (j & 15)) * 128;
    const int n0 = (j >> 4) * BN;

    // Swizzled staging source: slot q holds row 2*(q>>3)+(s>>2), elems
    // (s&3)*8.. where s = (q&7) ^ ((q>>3)&7). Slot q+256 -> same s, row+64.
    const int s0 = (tid & 7) ^ ((tid >> 3) & 7);
    const int srow = 2 * (tid >> 3) + (s0 >> 2);
    const int scol = (s0 & 3) * 8;
    const u16* AgS = A + (size_t)(m0 + srow) * K + scol;
    const u16* BgS = Bt + (size_t)(n0 + srow) * K + scol;  // NF==2: q<256, rows<64

    // Swizzled read offsets: logical (row R, chunk qd) at byte
    // (R>>1)*128 + ((((R&1)<<2)|qd) ^ ((R>>1)&7))*16
    int offA[4], offB[NF];
#pragma unroll
    for (int i = 0; i < 4; ++i) {
        int R = wy * 64 + i * 16 + l16;
        offA[i] = (R >> 1) * 128 + (((((R & 1) << 2) | qd) ^ ((R >> 1) & 7)) << 4);
    }
#pragma unroll
    for (int jj = 0; jj < NF; ++jj) {
        int R = wx * (BN / 2) + jj * 16 + l16;
        offB[jj] = (R >> 1) * 128 + (((((R & 1) << 2) | qd) ^ ((R >> 1) & 7)) << 4);
    }

    const floatx4 fz = {0.f, 0.f, 0.f, 0.f};
    floatx4 acc[4][NF];
#pragma unroll
    for (int i = 0; i < 4; ++i)
#pragma unroll
        for (int jj = 0; jj < NF; ++jj) acc[i][jj] = fz;

    auto stage = [&](int slot, int k0) {
#pragma unroll
        for (int kc = 0; kc < KC; ++kc) {
            char* Ad = (char*)&As[slot][kc][0];
            gl2lds16(AgS + k0 + kc * 32, Ad + tid * 16);
            gl2lds16(AgS + (size_t)64 * K + k0 + kc * 32, Ad + (tid + 256) * 16);
            char* Bd = (char*)&Bs[slot][kc][0];
            gl2lds16(BgS + k0 + kc * 32, Bd + tid * 16);
            if (NF == 4) gl2lds16(BgS + (size_t)64 * K + k0 + kc * 32, Bd + (tid + 256) * 16);
        }
    };

    stage(0, 0);
    const int iters = K / BK;
    for (int it = 0; it < iters; ++it) {
        const int slot = it & 1;
        __syncthreads();
        if (it + 1 < iters) stage(slot ^ 1, (it + 1) * BK);
#pragma unroll
        for (int kc = 0; kc < KC; ++kc) {
            const char* Ab = (const char*)&As[slot][kc][0];
            const char* Bb = (const char*)&Bs[slot][kc][0];
            short8 af[4], bfr[NF];
#pragma unroll
            for (int i = 0; i < 4; ++i) af[i] = *(const short8*)(Ab + offA[i]);
#pragma unroll
            for (int jj = 0; jj < NF; ++jj) bfr[jj] = *(const short8*)(Bb + offB[jj]);
            // swapped operands: D = C^T tile; lane -> (col=qd*4+r, row=l16)
#pragma unroll
            for (int i = 0; i < 4; ++i)
#pragma unroll
                for (int jj = 0; jj < NF; ++jj) acc[i][jj] = MFMA16(bfr[jj], af[i], acc[i][jj]);
        }
    }

    const int rowb = m0 + wy * 64 + l16;
    const int colb = n0 + wx * (BN / 2) + qd * 4;

    if constexpr (OUTMODE == 1 || OUTMODE == 3) {
        if (OUTMODE == 3 && n0 >= 2 * CDIM) {
            // V tile: direct transposed+swizzled stores into Vout (attn vT
            // layout): pos = d*1024 + (key&~63)|(key&7) + ((((key>>3)&7)^(d&7))<<3)
#pragma unroll
            for (int jj = 0; jj < NF; ++jj) {
                float4 bb = *(const float4*)(bias + colb + jj * 16);
#pragma unroll
                for (int i = 0; i < 4; ++i) {
                    floatx4 a = acc[i][jj];
                    int row = rowb + i * 16;
                    int b_ = row >> 10, key = row & 1023;
                    int kb = (key & ~63) | (key & 7);
                    int k3 = (key >> 3) & 7;
                    float vv[4] = {a[0] + bb.x, a[1] + bb.y, a[2] + bb.z, a[3] + bb.w};
#pragma unroll
                    for (int r = 0; r < 4; ++r) {
                        int cv = colb + jj * 16 + r - 2 * CDIM;  // V channel 0..383
                        int h = cv / DH, d = cv - h * DH;
                        Vout[((size_t)(b_ * NHEADS + h) * DH + d) * NPIX + kb +
                             ((k3 ^ (d & 7)) << 3)] = (u16)cvtpk(vv[r], vv[r]);
                    }
                }
            }
        } else {
            // LDS-staged coalesced bf16 epilogue (BN=128 instantiations).
            __syncthreads();  // all waves done reading As/Bs
            char* myl = (wv < 2) ? (char*)(&As[0][0][0]) + wv * 8192
                                 : (char*)(&Bs[0][0][0]) + (wv - 2) * 8192;
#pragma unroll
            for (int jj = 0; jj < NF; ++jj) {
                float4 bb = *(const float4*)(bias + colb + jj * 16);
#pragma unroll
                for (int i = 0; i < 4; ++i) {
                    floatx4 a = acc[i][jj];
                    float v0 = a[0] + bb.x, v1 = a[1] + bb.y, v2 = a[2] + bb.z, v3 = a[3] + bb.w;
                    if (ACT) {
                        v0 = gelu_f(v0);
                        v1 = gelu_f(v1);
                        v2 = gelu_f(v2);
                        v3 = gelu_f(v3);
                    }
                    int row_l = i * 16 + l16;
                    int cbyte = (jj * 32 + qd * 8) ^ ((row_l & 7) << 4);
                    uint2 pk;
                    pk.x = pkbf(v0, v1);
                    pk.y = pkbf(v2, v3);
                    *(uint2*)(myl + row_l * 128 + cbyte) = pk;
                }
            }
            __syncthreads();  // order LDS writes before reads
            const int rl0 = lane >> 3;
            const int cb = (lane & 7) * 16;
            __hip_bfloat16* Cb = (__hip_bfloat16*)Cout +
                                 (size_t)(m0 + wy * 64) * N + n0 + wx * 64 + (lane & 7) * 8;
#pragma unroll
            for (int rr8 = 0; rr8 < 8; ++rr8) {
                int row_l = rr8 * 8 + rl0;
                uint4 v = *(const uint4*)(myl + row_l * 128 + (cb ^ ((row_l & 7) << 4)));
                *(uint4*)(Cb + (size_t)row_l * N) = v;
            }
        }
    } else {
#pragma unroll
        for (int jj = 0; jj < NF; ++jj) {
            int col = colb + jj * 16;
            float4 bb = *(const float4*)(bias + col);
#pragma unroll
            for (int i = 0; i < 4; ++i) {
                int row = rowb + i * 16;
                floatx4 a = acc[i][jj];
                float v0 = a[0] + bb.x, v1 = a[1] + bb.y, v2 = a[2] + bb.z, v3 = a[3] + bb.w;
                if (RES) {
                    uint2 rv = *(const uint2*)(Res + (size_t)row * N + col);
                    v0 += bf2f((u16)(rv.x & 0xFFFF));
                    v1 += bf2f((u16)(rv.x >> 16));
                    v2 += bf2f((u16)(rv.y & 0xFFFF));
                    v3 += bf2f((u16)(rv.y >> 16));
                }
                if (ACT) {
                    v0 = gelu_f(v0);
                    v1 = gelu_f(v1);
                    v2 = gelu_f(v2);
                    v3 = gelu_f(v3);
                }
                if (OUTMODE == 0) {
                    // bf16 row-major residual stream
                    uint2 pk;
                    pk.x = pkbf(v0, v1);
                    pk.y = pkbf(v2, v3);
                    *(uint2*)((u16*)Cout + (size_t)row * N + col) = pk;
                } else {
                    // NCHW: out[b][c][p]; lane holds 4 consecutive channels at pixel row
                    int b_ = row >> 10, p = row & 1023;
                    float* op = (float*)Cout + ((size_t)(b_ * CDIM + col)) * NPIX + p;
                    op[0] = v0;
                    op[NPIX] = v1;
                    op[2 * NPIX] = v2;
                    op[3 * NPIX] = v3;
                }
            }
        }
    }
}

// ---------------------------------------------------------------------------
// MFMA flash attention: triple-buffered K/V, prefetch distance 2, counted
// per-wave vmcnt + 2x q-block coverage (256 q-rows/block, grid 512).
// ---------------------------------------------------------------------------
__global__ __launch_bounds__(256) void attn_kernel(const u16* __restrict__ qkv,
                                                   const u16* __restrict__ vT,
                                                   __hip_bfloat16* __restrict__ ob) {
    const int id = blockIdx.x;
    const int h = id & 7;
    const int b = (id >> 3) & 15;
    const int qb = id >> 7;                      // [0,4): 256-row q-block
    const int tid = threadIdx.x;
    const int lane = tid & 63, wv = tid >> 6;
    const int qd = lane >> 4, l16 = lane & 15;

    __shared__ u16 Kl[3][65 * 48];               // 3-buf [key][d] + safety row
    __shared__ u16 Vt[3][48 * 64];               // 3-buf [d][key], swizzled image

    const size_t bh = (size_t)b * NPIX * QKVN + (size_t)h * DH;
    const u16* vtb = vT + (size_t)(b * NHEADS + h) * DH * NPIX;

    auto stageK = [&](int kt, int slot) {
        const size_t kbase = bh + (size_t)(kt * 64) * QKVN + CDIM;
        int key = tid / 6, ch = tid - key * 6;
        gl2lds16(qkv + kbase + (size_t)key * QKVN + ch * 8, &Kl[slot][0] + tid * 8);
        if (tid < 128) {
            int t2 = tid + 256;
            int k2 = t2 / 6, c2 = t2 - k2 * 6;
            gl2lds16(qkv + kbase + (size_t)k2 * QKVN + c2 * 8, &Kl[slot][0] + t2 * 8);
        }
    };
    auto stageV = [&](int kt, int slot) {
        const u16* vbase = vtb + (size_t)kt * 64 + (tid & 7) * 8;
        gl2lds16(vbase + (size_t)(tid >> 3) * NPIX, &Vt[slot][0] + tid * 8);
        if (tid < 128)
            gl2lds16(vbase + (size_t)((tid + 256) >> 3) * NPIX, &Vt[slot][0] + (tid + 256) * 8);
    };

    // Q fragments (B-operand), 4 16-row groups covering 256 q-rows:
    // row = qb*256 + (g2>>1)*128 + wv*32 + (g2&1)*16 + l16
    const float qsc = 0.14433756729740643f * 1.4426950408889634f;
    short8 qf[4][2];
    const short8 z8 = {0, 0, 0, 0, 0, 0, 0, 0};
#pragma unroll
    for (int g2 = 0; g2 < 4; ++g2) {
        const int qrow = qb * 256 + (g2 >> 1) * 128 + wv * 32 + (g2 & 1) * 16 + l16;
        const u16* gq = qkv + bh + (size_t)qrow * QKVN;
        short8 q0 = *(const short8*)(gq + qd * 8);
        short8 q1 = (qd < 2) ? *(const short8*)(gq + 32 + qd * 8) : z8;
        uintx4 u0 = __builtin_bit_cast(uintx4, q0);
        uintx4 u1 = __builtin_bit_cast(uintx4, q1);
#pragma unroll
        for (int w = 0; w < 4; ++w) {
            u0[w] = cvtpk(bf2f((u16)(u0[w] & 0xFFFF)) * qsc, bf2f((u16)(u0[w] >> 16)) * qsc);
            u1[w] = cvtpk(bf2f((u16)(u1[w] & 0xFFFF)) * qsc, bf2f((u16)(u1[w] >> 16)) * qsc);
        }
        qf[g2][0] = __builtin_bit_cast(short8, u0);
        qf[g2][1] = __builtin_bit_cast(short8, u1);
    }

    const floatx4 fz = {0.f, 0.f, 0.f, 0.f};
    floatx4 o[4][3];
    floatx4 lacc[4];
    const short8 ones8 = {0x3F80, 0x3F80, 0x3F80, 0x3F80, 0x3F80, 0x3F80, 0x3F80, 0x3F80};
#pragma unroll
    for (int g2 = 0; g2 < 4; ++g2) {
        lacc[g2] = fz;
#pragma unroll
        for (int nt = 0; nt < 3; ++nt) o[g2][nt] = fz;
    }

    // prologue: two stages in flight (prefetch distance 2)
    stageK(0, 0); stageV(0, 0);
    stageK(1, 1); stageV(1, 1);
    const int sw = l16 & 7;

    for (int kt = 0; kt < 16; ++kt) {
        const int cur = kt % 3;
        // Wait for stage(kt) only (stage(kt+1) stays in flight), then barrier.
        // Waves 0-1 issue 4 gl2lds per stage, waves 2-3 issue 2.
        if (kt + 1 < 16) {
            if (wv < 2) asm volatile("s_waitcnt vmcnt(4)\ns_barrier" ::: "memory");
            else        asm volatile("s_waitcnt vmcnt(2)\ns_barrier" ::: "memory");
        } else {
            asm volatile("s_waitcnt vmcnt(0)\ns_barrier" ::: "memory");
        }
        // issue stage(kt+2) into the slot last read at kt-1 (safe: all waves
        // passed the barrier, their kt-1 LDS reads are complete)
        if (kt + 2 < 16) {
            int ns = (kt + 2) % 3;
            stageK(kt + 2, ns);
            stageV(kt + 2, ns);
        }

        // K fragments (A-operand: m=key); overread d>=48 multiplied by qf1=0
        short8 kl[4], kh[4];
#pragma unroll
        for (int t = 0; t < 4; ++t) {
            const u16* kr = &Kl[cur][0] + (t * 16 + l16) * 48;
            kl[t] = *(const short8*)(kr + qd * 8);
            kh[t] = *(const short8*)(kr + 32 + qd * 8);
        }
        // V fragments (A-operand for PV: m=d); swizzled chunk position
        short8 vl[3], vh[3];
#pragma unroll
        for (int nt = 0; nt < 3; ++nt) {
            const u16* vr = &Vt[cur][0] + (nt * 16 + l16) * 64;
            vl[nt] = *(const short8*)(vr + (qd ^ sw) * 8);
            vh[nt] = *(const short8*)(vr + ((qd + 4) ^ sw) * 8);
        }

#pragma unroll
        for (int g2 = 0; g2 < 4; ++g2) {
            // S^T tiles: lane -> (key = t*16+qd*4+r, query = l16)
            u32 pw[4][2];
#pragma unroll
            for (int t = 0; t < 4; ++t) {
                floatx4 a = fz;
                a = MFMA16(kl[t], qf[g2][0], a);
                a = MFMA16(kh[t], qf[g2][1], a);
                float p0 = __builtin_amdgcn_exp2f(a[0]);
                float p1 = __builtin_amdgcn_exp2f(a[1]);
                float p2 = __builtin_amdgcn_exp2f(a[2]);
                float p3 = __builtin_amdgcn_exp2f(a[3]);
                pw[t][0] = cvtpk(p0, p1);  // keys t*16+qd*4+{0,1}, query l16
                pw[t][1] = cvtpk(p2, p3);  // keys t*16+qd*4+{2,3}
            }
            // In-register P^T redistribution: perfect shuffle of 16-lane groups.
            u32 apw[8];
#pragma unroll
            for (int hb2 = 0; hb2 < 2; ++hb2) {
#pragma unroll
                for (int w = 0; w < 2; ++w) {
                    uintx2 P = __builtin_amdgcn_permlane32_swap(
                        pw[2 * hb2][w], pw[2 * hb2 + 1][w], false, false);
                    uintx2 R = __builtin_amdgcn_permlane16_swap(P.x, P.y, false, false);
                    apw[hb2 * 4 + w] = R.x;
                    apw[hb2 * 4 + w + 2] = R.y;
                }
            }
            uintx4 a0v = {apw[0], apw[1], apw[2], apw[3]};
            uintx4 a1v = {apw[4], apw[5], apw[6], apw[7]};
            short8 ap0 = __builtin_bit_cast(short8, a0v);
            short8 ap1 = __builtin_bit_cast(short8, a1v);
            // PV: O^T accumulate; denominator on MFMA pipe (ones-row trick)
#pragma unroll
            for (int nt = 0; nt < 3; ++nt) {
                o[g2][nt] = MFMA16(vl[nt], ap0, o[g2][nt]);
                o[g2][nt] = MFMA16(vh[nt], ap1, o[g2][nt]);
            }
            lacc[g2] = MFMA16(ones8, ap0, lacc[g2]);
            lacc[g2] = MFMA16(ones8, ap1, lacc[g2]);
        }
    }

    // epilogue: lane holds O^T[d=nt*16+qd*4+r][query=l16]; lacc rows identical
    // = full denominator for query l16 (no cross-lane reduction needed).
#pragma unroll
    for (int g2 = 0; g2 < 4; ++g2) {
        float inv = 1.f / lacc[g2][0];
        const int qrow = qb * 256 + (g2 >> 1) * 128 + wv * 32 + (g2 & 1) * 16 + l16;
        __hip_bfloat16* orow = ob + (size_t)(b * NPIX + qrow) * CDIM + h * DH;
#pragma unroll
        for (int nt = 0; nt < 3; ++nt) {
            float v0 = o[g2][nt][0] * inv, v1 = o[g2][nt][1] * inv;
            float v2 = o[g2][nt][2] * inv, v3 = o[g2][nt][3] * inv;
            uint2 w;
            w.x = cvtpk(v0, v1);
            w.y = cvtpk(v2, v3);
            *(uint2*)(orow + nt * 16 + qd * 4) = w;
        }
    }
}

// ---------------------------------------------------------------------------
extern "C" void kernel_launch(void* const* d_in, const int* in_sizes, int n_in,
                              void* d_out, int out_size, void* d_ws, size_t ws_size,
                              hipStream_t stream) {
    const float* x = (const float*)d_in[0];
    const float* pos_w = (const float*)d_in[1];
    const float* pos_b = (const float*)d_in[2];
    const float* g1 = (const float*)d_in[3];
    const float* b1 = (const float*)d_in[4];
    const float* wqkv = (const float*)d_in[5];
    const float* bqkv = (const float*)d_in[6];
    const float* wproj = (const float*)d_in[7];
    const float* bproj = (const float*)d_in[8];
    const float* g2 = (const float*)d_in[9];
    const float* b2 = (const float*)d_in[10];
    const float* w1 = (const float*)d_in[11];
    const float* bf1 = (const float*)d_in[12];
    const float* w2 = (const float*)d_in[13];
    const float* bf2 = (const float*)d_in[14];
    float* out = (float*)d_out;

    char* ws = (char*)d_ws;
    u16* t = (u16*)ws;                                          // [0, 12.6MB) BF16 residual stream
    __hip_bfloat16* xn = (__hip_bfloat16*)(ws + 25165824);      // LN out; dead after its GEMM
    __hip_bfloat16* obb = (__hip_bfloat16*)(ws + 25165824);     // attn out REUSES xn slot
    __hip_bfloat16* wqkvT = (__hip_bfloat16*)(ws + 37748736);
    __hip_bfloat16* wprojT = (__hip_bfloat16*)(ws + 38633472);
    __hip_bfloat16* w1T = (__hip_bfloat16*)(ws + 38928384);
    __hip_bfloat16* w2T = (__hip_bfloat16*)(ws + 40108032);
    char* big = ws + 41287680;
    u16* qkvb = (u16*)big;                                      // [41.3, 79.0MB)
    u16* vTb = (u16*)(big + 37748736);                          // [79.0, 91.6MB) fused vtrans out
    u16* hb = (u16*)big;                                        // mlp1 out reuses qkvb (dead)

    wt_all_kernel<<<dim3(1728), 256, 0, stream>>>(wqkv, wproj, w1, w2,
                                                  wqkvT, wprojT, w1T, w2T);
    conv_pe_kernel<<<dim3(CDIM / 64, HH, BATCH), 256, 0, stream>>>(x, pos_w, pos_b, t);
    ln_kernel<<<MTOK, 128, 0, stream>>>(t, g1, b1, xn);
    // qkv: Q/K tiles -> qkvb rows; V tiles -> vTb transposed+swizzled (fused)
    gemm_bf16<128, 32, 0, 0, 3><<<dim3(128 * (QKVN / 128)), 256, 0, stream>>>(
        (const u16*)xn, (const u16*)wqkvT, bqkv, nullptr, qkvb, vTb, QKVN, CDIM);
    attn_kernel<<<dim3(512), 256, 0, stream>>>(qkvb, vTb, obb);
    // proj: bf16 out + bf16 residual (t)
    gemm_bf16<64, 64, 1, 0, 0><<<dim3(128 * (CDIM / 64)), 256, 0, stream>>>(
        (const u16*)obb, (const u16*)wprojT, bproj, t, t, nullptr, CDIM, CDIM);
    ln_kernel<<<MTOK, 128, 0, stream>>>(t, g2, b2, xn);
    gemm_bf16<128, 32, 0, 1, 1><<<dim3(128 * (FFN / 128)), 256, 0, stream>>>(
        (const u16*)xn, (const u16*)w1T, bf1, nullptr, hb, nullptr, FFN, CDIM);
    // mlp2 writes the NCHW output directly (bf16 residual from t)
    gemm_bf16<64, 64, 1, 0, 2><<<dim3(128 * (CDIM / 64)), 256, 0, stream>>>(
        (const u16*)hb, (const u16*)w2T, bf2, t, out, nullptr, CDIM, FFN);
}